// Round 6
// baseline (368.259 us; speedup 1.0000x reference)
//
#include <hip/hip_runtime.h>

#define B_ 8
#define L_ 2048
#define CIN_ 256
#define COUT_ 256
#define HEADS_ 4
#define HD_ 64
#define NEG_SLOPE_ 0.2f

#define TI 32   // proj i-rows per block
#define TJ 64   // attn j-cols per tile
#define NJT (L_ / TJ)

typedef __attribute__((ext_vector_type(4))) float f32x4;
typedef __attribute__((ext_vector_type(8))) __bf16 bf16x8;
typedef __attribute__((ext_vector_type(4))) __bf16 bf16x4;

// MFMA 16x16x32 bf16 layouts (m89/m120-verified):
//  A[m][k]: m = lane&15, k = (lane>>4)*8 + e
//  B[k][n]: n = lane&15, k = (lane>>4)*8 + e
//  D[m][n]: n = lane&15, m = (lane>>4)*4 + reg

// ---------------------------------------------------------------------------
// Kernel 1 (unchanged, passing): h = x@W^T via MFMA -> hT[b][c][l] bf16
// + fused fp32 a_src/a_dst.
// ---------------------------------------------------------------------------
__global__ __launch_bounds__(256, 2)
void proj_kernel(const float* __restrict__ x, const float* __restrict__ W,
                 const float* __restrict__ att_src, const float* __restrict__ att_dst,
                 __bf16* __restrict__ hT, float* __restrict__ a_src,
                 float* __restrict__ a_dst) {
  __shared__ __align__(16) __bf16 Wl[COUT_][80];
  __shared__ __align__(16) __bf16 Al[2][2][512];
  __shared__ __align__(16) __bf16 Tl[4][64][48];  // stride 96 B (16B multiple)

  const int tid = threadIdx.x;
  const int r0 = blockIdx.x * TI;
  const int b  = r0 >> 11;
  const int l0 = r0 & (L_ - 1);

  const int w = tid >> 6, lane = tid & 63, col = lane & 15, q = lane >> 4;
  const int si = tid >> 3, soct = tid & 7;
  const int wn = tid >> 2, wkq = tid & 3;

  f32x4 acc[2][4];
#pragma unroll
  for (int mt = 0; mt < 2; ++mt)
#pragma unroll
    for (int nt = 0; nt < 4; ++nt) acc[mt][nt] = (f32x4)0.f;

  for (int kc = 0; kc < CIN_ / 64; ++kc) {
    __syncthreads();
#pragma unroll
    for (int rg = 0; rg < 4; ++rg) {
      const int row = rg * 64 + wn;
      const float4* ws = (const float4*)(W + (size_t)row * CIN_ + kc * 64 + wkq * 16);
#pragma unroll
      for (int u = 0; u < 4; ++u) {
        float4 f = ws[u];
        bf16x4 v;
        v[0] = (__bf16)f.x; v[1] = (__bf16)f.y; v[2] = (__bf16)f.z; v[3] = (__bf16)f.w;
        *(bf16x4*)&Wl[row][wkq * 16 + u * 4] = v;
      }
    }
    {
      const float4* xs = (const float4*)(x + (size_t)(r0 + si) * CIN_ + kc * 64 + soct * 8);
      float4 f0 = xs[0], f1 = xs[1];
      bf16x8 v;
      v[0] = (__bf16)f0.x; v[1] = (__bf16)f0.y; v[2] = (__bf16)f0.z; v[3] = (__bf16)f0.w;
      v[4] = (__bf16)f1.x; v[5] = (__bf16)f1.y; v[6] = (__bf16)f1.z; v[7] = (__bf16)f1.w;
      *(bf16x8*)&Al[si >> 4][soct >> 2][(((soct & 3) << 4) + (si & 15)) << 3] = v;
    }
    __syncthreads();

    bf16x8 af[2][2], bfr[2][4];
#pragma unroll
    for (int mt = 0; mt < 2; ++mt)
#pragma unroll
      for (int kt = 0; kt < 2; ++kt)
        af[mt][kt] = *(const bf16x8*)&Al[mt][kt][lane << 3];
#pragma unroll
    for (int kt = 0; kt < 2; ++kt)
#pragma unroll
      for (int nt = 0; nt < 4; ++nt)
        bfr[kt][nt] = *(const bf16x8*)&Wl[w * 64 + nt * 16 + col][kt * 32 + q * 8];
#pragma unroll
    for (int kt = 0; kt < 2; ++kt)
#pragma unroll
      for (int mt = 0; mt < 2; ++mt)
#pragma unroll
        for (int nt = 0; nt < 4; ++nt)
          acc[mt][nt] = __builtin_amdgcn_mfma_f32_16x16x32_bf16(
              af[mt][kt], bfr[kt][nt], acc[mt][nt], 0, 0, 0);
  }

  float asv[4], adv[4];
#pragma unroll
  for (int nt = 0; nt < 4; ++nt) {
    asv[nt] = att_src[w * 64 + nt * 16 + col];
    adv[nt] = att_dst[w * 64 + nt * 16 + col];
  }
#pragma unroll
  for (int mt = 0; mt < 2; ++mt)
#pragma unroll
    for (int reg = 0; reg < 4; ++reg) {
      float s = 0.f, d = 0.f;
#pragma unroll
      for (int nt = 0; nt < 4; ++nt) {
        s = fmaf(acc[mt][nt][reg], asv[nt], s);
        d = fmaf(acc[mt][nt][reg], adv[nt], d);
      }
      s += __shfl_xor(s, 1, 64); d += __shfl_xor(d, 1, 64);
      s += __shfl_xor(s, 2, 64); d += __shfl_xor(d, 2, 64);
      s += __shfl_xor(s, 4, 64); d += __shfl_xor(d, 4, 64);
      s += __shfl_xor(s, 8, 64); d += __shfl_xor(d, 8, 64);
      if (col == 0) {
        int il = mt * 16 + q * 4 + reg;
        a_src[((size_t)(b * HEADS_ + w) << 11) + l0 + il] = s;
        a_dst[((size_t)(b * HEADS_ + w) << 11) + l0 + il] = d;
      }
    }

#pragma unroll
  for (int mt = 0; mt < 2; ++mt)
#pragma unroll
    for (int nt = 0; nt < 4; ++nt)
#pragma unroll
      for (int reg = 0; reg < 4; ++reg)
        Tl[w][nt * 16 + col][mt * 16 + q * 4 + reg] = (__bf16)acc[mt][nt][reg];
  __syncthreads();
  {
    const size_t hrow = ((size_t)(b * COUT_ + w * 64 + lane) << 11) + l0;
#pragma unroll
    for (int u = 0; u < 4; ++u) {
      uint4 v = *(const uint4*)&Tl[w][lane][u * 8];
      *(uint4*)(hT + hrow + u * 8) = v;
    }
  }
}

// ---------------------------------------------------------------------------
// Kernel 2 (R6): fully wave-independent attention. NO LDS, NO loop barriers.
// grid 512 = B x (L/32), 512 thr. Block = 32 i-rows; wave w: head hh = w>>1,
// 16-row strip half = w&1. Each lane computes the P values of ITS OWN MFMA
// A-fragment in registers: m = lane&15 (row), k = q*8+e (+32*kt) (col j).
// Per j-tile: 8 B-frag loads (L2-resident hT), 4 adst loads (L2), 4 adj int4
// (HBM, prefetched one tile ahead, issued LAST so L2-load waits don't drain
// it), 16 exp, 8 MFMA. l per-lane, shuffle-reduced; epilogue divides.
// adj is read once per head (4x L2 amplification, same HBM bytes).
// ---------------------------------------------------------------------------
__global__ __launch_bounds__(512, 4)
void attn_kernel(const __bf16* __restrict__ hT, const float* __restrict__ a_src,
                 const float* __restrict__ a_dst, const int* __restrict__ adj,
                 float* __restrict__ out) {
  const int tid = threadIdx.x;
  const int b  = blockIdx.x & 7;           // XCD swizzle: batch b per XCD
  const int i0 = (blockIdx.x >> 3) * 32;   // 32-row block

  const int w = tid >> 6, lane = tid & 63, col = lane & 15, q = lane >> 4;
  const int hh = w >> 1;                   // head
  const int half = w & 1;                  // 16-row strip within block
  const int rA = i0 + half * 16 + col;     // this lane's P row (A-frag m)

  const float asr = a_src[((size_t)(b * HEADS_ + hh) << 11) + rA];
  const int* adjrow = adj + ((size_t)b * L_ + rA) * L_ + q * 8;
  const float* adb  = a_dst + ((size_t)(b * HEADS_ + hh) << 11) + q * 8;
  const __bf16* hbase = hT + ((size_t)(b * COUT_ + hh * 64) << 11);

  float lacc = 0.f;
  f32x4 acc[4];
#pragma unroll
  for (int nt = 0; nt < 4; ++nt) acc[nt] = (f32x4)0.f;

  // prologue: adj for tile 0
  int4 cadj[2][2];
#pragma unroll
  for (int kt = 0; kt < 2; ++kt) {
    cadj[kt][0] = *(const int4*)(adjrow + kt * 32);
    cadj[kt][1] = *(const int4*)(adjrow + kt * 32 + 4);
  }

  for (int jt = 0; jt < NJT; ++jt) {
    const int j0 = jt * TJ;
    const int jn = ((jt < NJT - 1) ? jt + 1 : jt) * TJ;

    // (1) B-frags for this tile: L2-resident hT, 16 B each
    bf16x8 bfr[2][4];
#pragma unroll
    for (int kt = 0; kt < 2; ++kt)
#pragma unroll
      for (int nt = 0; nt < 4; ++nt)
        bfr[kt][nt] = *(const bf16x8*)(hbase + ((size_t)(nt * 16 + col) << 11) +
                                       j0 + kt * 32 + q * 8);
    // (2) a_dst for this tile (L2)
    float4 dv[2][2];
#pragma unroll
    for (int kt = 0; kt < 2; ++kt) {
      dv[kt][0] = *(const float4*)(adb + j0 + kt * 32);
      dv[kt][1] = *(const float4*)(adb + j0 + kt * 32 + 4);
    }
    // (3) next-tile adj LAST (HBM ~900cyc): FIFO vmcnt means waiting on (2)
    //     leaves these in flight; consumed next iteration.
    int4 nadj[2][2];
#pragma unroll
    for (int kt = 0; kt < 2; ++kt) {
      nadj[kt][0] = *(const int4*)(adjrow + jn + kt * 32);
      nadj[kt][1] = *(const int4*)(adjrow + jn + kt * 32 + 4);
    }

    // phase 1: P values in A-frag register order
    bf16x8 av[2];
#pragma unroll
    for (int kt = 0; kt < 2; ++kt) {
      const int am[8] = {cadj[kt][0].x, cadj[kt][0].y, cadj[kt][0].z, cadj[kt][0].w,
                         cadj[kt][1].x, cadj[kt][1].y, cadj[kt][1].z, cadj[kt][1].w};
      const float dd[8] = {dv[kt][0].x, dv[kt][0].y, dv[kt][0].z, dv[kt][0].w,
                           dv[kt][1].x, dv[kt][1].y, dv[kt][1].z, dv[kt][1].w};
#pragma unroll
      for (int e = 0; e < 8; ++e) {
        float s = asr + dd[e];
        s = fmaxf(s, NEG_SLOPE_ * s);        // leaky relu
        float p = am[e] ? __expf(s) : 0.f;   // bounded scores, no overflow
        lacc += p;
        av[kt][e] = (__bf16)p;
      }
    }

    // phase 2: 8 MFMA, acc += P @ h
#pragma unroll
    for (int kt = 0; kt < 2; ++kt)
#pragma unroll
      for (int nt = 0; nt < 4; ++nt)
        acc[nt] = __builtin_amdgcn_mfma_f32_16x16x32_bf16(av[kt], bfr[kt][nt],
                                                          acc[nt], 0, 0, 0);
#pragma unroll
    for (int kt = 0; kt < 2; ++kt) {
      cadj[kt][0] = nadj[kt][0];
      cadj[kt][1] = nadj[kt][1];
    }
  }

  // l: reduce across the 4 q-lanes sharing each row (lanes r, r+16, r+32, r+48)
  lacc += __shfl_xor(lacc, 16, 64);
  lacc += __shfl_xor(lacc, 32, 64);
  // now every lane holds the full row-sum for row rA (keyed by lane&15)

  // epilogue: D row m = q*4+reg, col n = lane&15; l for row m from lane m
#pragma unroll
  for (int reg = 0; reg < 4; ++reg) {
    const int m = q * 4 + reg;
    const float linv = 1.0f / __shfl(lacc, m, 64);
    const size_t orow = ((size_t)(b * L_ + i0 + half * 16 + m)) * COUT_ + hh * 64;
#pragma unroll
    for (int nt = 0; nt < 4; ++nt)
      out[orow + nt * 16 + col] = acc[nt][reg] * linv;
  }
}

// ---------------------------------------------------------------------------
extern "C" void kernel_launch(void* const* d_in, const int* in_sizes, int n_in,
                              void* d_out, int out_size, void* d_ws, size_t ws_size,
                              hipStream_t stream) {
  const float* x       = (const float*)d_in[0];
  const int*   adj     = (const int*)d_in[1];
  const float* W       = (const float*)d_in[2];
  const float* att_src = (const float*)d_in[3];
  const float* att_dst = (const float*)d_in[4];
  float* out = (float*)d_out;

  __bf16* hT   = (__bf16*)d_ws;                             // 8 MB [b][c][l]
  float* a_src = (float*)((char*)d_ws + (size_t)B_ * COUT_ * L_ * 2);
  float* a_dst = a_src + (size_t)B_ * HEADS_ * L_;

  proj_kernel<<<(B_ * L_) / TI, 256, 0, stream>>>(x, W, att_src, att_dst, hT, a_src, a_dst);
  attn_kernel<<<B_ * (L_ / 32), 512, 0, stream>>>(hT, a_src, a_dst, adj, out);
}

// Round 7
// 267.257 us; speedup vs baseline: 1.3779x; 1.3779x over previous
//
#include <hip/hip_runtime.h>

#define B_ 8
#define L_ 2048
#define CIN_ 256
#define COUT_ 256
#define HEADS_ 4
#define HD_ 64
#define NEG_SLOPE_ 0.2f

#define TI 32   // proj i-rows per block
#define TJ 64   // attn j-cols per tile
#define NJT (L_ / TJ)

typedef __attribute__((ext_vector_type(4))) float f32x4;
typedef __attribute__((ext_vector_type(8))) __bf16 bf16x8;
typedef __attribute__((ext_vector_type(4))) __bf16 bf16x4;

// MFMA 16x16x32 bf16 layouts (m89/m120-verified):
//  A[m][k]: m = lane&15, k = (lane>>4)*8 + e
//  B[k][n]: n = lane&15, k = (lane>>4)*8 + e
//  D[m][n]: n = lane&15, m = (lane>>4)*4 + reg
//
// hF ("B-frag-linear" h): for (b,h,jt,kt,nt) a 512-elem block, element
// (q*16+col)*8+e = h[channel h*64+nt*16+col][j = jt*64+kt*32+q*8+e].
// attn loads one whole block per (kt,nt) as lane*16B contiguous -> coalesced.

// ---------------------------------------------------------------------------
// Kernel 0: pack adj int32 -> 1 bit (uint64 words, natural j order).
// wave handles 256 ints via 4 coalesced dword loads + 4 ballots.
// ---------------------------------------------------------------------------
__global__ __launch_bounds__(256, 4)
void pack_kernel(const int* __restrict__ adj, unsigned long long* __restrict__ abits) {
  const size_t wid = ((size_t)blockIdx.x * 256 + threadIdx.x) >> 6;
  const int lane = threadIdx.x & 63;
  const int* p = adj + wid * 256 + lane;
  unsigned long long b0 = __ballot(p[0]   != 0);
  unsigned long long b1 = __ballot(p[64]  != 0);
  unsigned long long b2 = __ballot(p[128] != 0);
  unsigned long long b3 = __ballot(p[192] != 0);
  if (lane == 0) {
    ulonglong2 v01; v01.x = b0; v01.y = b1;
    ulonglong2 v23; v23.x = b2; v23.y = b3;
    *(ulonglong2*)(abits + wid * 4)     = v01;
    *(ulonglong2*)(abits + wid * 4 + 2) = v23;
  }
}

// ---------------------------------------------------------------------------
// Kernel 1: h = x@W^T via MFMA -> hF (B-frag-linear bf16) + fp32 a_src/a_dst.
// grid 512 x 256 thr; block = 32 seq rows (= attn j's), wave w = head w.
// Block covers exactly (jt = l0>>6, kt = (l0>>5)&1) of the attn frag space.
// ---------------------------------------------------------------------------
__global__ __launch_bounds__(256, 2)
void proj_kernel(const float* __restrict__ x, const float* __restrict__ W,
                 const float* __restrict__ att_src, const float* __restrict__ att_dst,
                 __bf16* __restrict__ hF, float* __restrict__ a_src,
                 float* __restrict__ a_dst) {
  __shared__ __align__(16) __bf16 Wl[COUT_][80];
  __shared__ __align__(16) __bf16 Al[2][2][512];

  const int tid = threadIdx.x;
  const int r0 = blockIdx.x * TI;
  const int b  = r0 >> 11;
  const int l0 = r0 & (L_ - 1);

  const int w = tid >> 6, lane = tid & 63, col = lane & 15, q = lane >> 4;
  const int si = tid >> 3, soct = tid & 7;
  const int wn = tid >> 2, wkq = tid & 3;

  f32x4 acc[2][4];
#pragma unroll
  for (int mt = 0; mt < 2; ++mt)
#pragma unroll
    for (int nt = 0; nt < 4; ++nt) acc[mt][nt] = (f32x4)0.f;

  for (int kc = 0; kc < CIN_ / 64; ++kc) {
    __syncthreads();
#pragma unroll
    for (int rg = 0; rg < 4; ++rg) {
      const int row = rg * 64 + wn;
      const float4* ws = (const float4*)(W + (size_t)row * CIN_ + kc * 64 + wkq * 16);
#pragma unroll
      for (int u = 0; u < 4; ++u) {
        float4 f = ws[u];
        bf16x4 v;
        v[0] = (__bf16)f.x; v[1] = (__bf16)f.y; v[2] = (__bf16)f.z; v[3] = (__bf16)f.w;
        *(bf16x4*)&Wl[row][wkq * 16 + u * 4] = v;
      }
    }
    {
      const float4* xs = (const float4*)(x + (size_t)(r0 + si) * CIN_ + kc * 64 + soct * 8);
      float4 f0 = xs[0], f1 = xs[1];
      bf16x8 v;
      v[0] = (__bf16)f0.x; v[1] = (__bf16)f0.y; v[2] = (__bf16)f0.z; v[3] = (__bf16)f0.w;
      v[4] = (__bf16)f1.x; v[5] = (__bf16)f1.y; v[6] = (__bf16)f1.z; v[7] = (__bf16)f1.w;
      *(bf16x8*)&Al[si >> 4][soct >> 2][(((soct & 3) << 4) + (si & 15)) << 3] = v;
    }
    __syncthreads();

    bf16x8 af[2][2], bfr[2][4];
#pragma unroll
    for (int mt = 0; mt < 2; ++mt)
#pragma unroll
      for (int kt = 0; kt < 2; ++kt)
        af[mt][kt] = *(const bf16x8*)&Al[mt][kt][lane << 3];
#pragma unroll
    for (int kt = 0; kt < 2; ++kt)
#pragma unroll
      for (int nt = 0; nt < 4; ++nt)
        bfr[kt][nt] = *(const bf16x8*)&Wl[w * 64 + nt * 16 + col][kt * 32 + q * 8];
#pragma unroll
    for (int kt = 0; kt < 2; ++kt)
#pragma unroll
      for (int mt = 0; mt < 2; ++mt)
#pragma unroll
        for (int nt = 0; nt < 4; ++nt)
          acc[mt][nt] = __builtin_amdgcn_mfma_f32_16x16x32_bf16(
              af[mt][kt], bfr[kt][nt], acc[mt][nt], 0, 0, 0);
  }

  // ---- fused a_src / a_dst ----
  float asv[4], adv[4];
#pragma unroll
  for (int nt = 0; nt < 4; ++nt) {
    asv[nt] = att_src[w * 64 + nt * 16 + col];
    adv[nt] = att_dst[w * 64 + nt * 16 + col];
  }
#pragma unroll
  for (int mt = 0; mt < 2; ++mt)
#pragma unroll
    for (int reg = 0; reg < 4; ++reg) {
      float s = 0.f, d = 0.f;
#pragma unroll
      for (int nt = 0; nt < 4; ++nt) {
        s = fmaf(acc[mt][nt][reg], asv[nt], s);
        d = fmaf(acc[mt][nt][reg], adv[nt], d);
      }
      s += __shfl_xor(s, 1, 64); d += __shfl_xor(d, 1, 64);
      s += __shfl_xor(s, 2, 64); d += __shfl_xor(d, 2, 64);
      s += __shfl_xor(s, 4, 64); d += __shfl_xor(d, 4, 64);
      s += __shfl_xor(s, 8, 64); d += __shfl_xor(d, 8, 64);
      if (col == 0) {
        int il = mt * 16 + q * 4 + reg;
        a_src[((size_t)(b * HEADS_ + w) << 11) + l0 + il] = s;
        a_dst[((size_t)(b * HEADS_ + w) << 11) + l0 + il] = d;
      }
    }

  // ---- hF write: D-frag -> B-frag-linear, direct dense global stores ----
  // m_local = mt*16 + q*4 + reg ; q' = mt*2 + (q>>1) ; e = (q&1)*4 + reg
  {
    const int jt_p = l0 >> 6;
    const int kt_p = (l0 >> 5) & 1;
    const int qhi = q >> 1, qlo = q & 1;
#pragma unroll
    for (int mt = 0; mt < 2; ++mt) {
      const int qp = mt * 2 + qhi;
#pragma unroll
      for (int nt = 0; nt < 4; ++nt) {
        bf16x4 v;
        v[0] = (__bf16)acc[mt][nt][0];
        v[1] = (__bf16)acc[mt][nt][1];
        v[2] = (__bf16)acc[mt][nt][2];
        v[3] = (__bf16)acc[mt][nt][3];
        const size_t off =
            ((((size_t)(b * HEADS_ + w) * 32 + jt_p) * 2 + kt_p) * 4 + nt) * 512 +
            (qp * 16 + col) * 8 + qlo * 4;
        *(bf16x4*)(hF + off) = v;
      }
    }
  }
}

// ---------------------------------------------------------------------------
// Kernel 2 (R7): barrier-free attention with coalesced everything.
// grid 512 = B x (L/32), 256 thr (4 waves). Wave w = head w, 32 i-rows.
// Per j-tile: 8 contiguous 1KB hF B-frag loads, 4 broadcast a_dst float4,
// 2 x 8B bitmask words; 32 exp/lane; 16 MFMA. Next tile prefetched before
// computing current (non-zero vmcnt waits). l per-lane -> shuffle reduce.
// ---------------------------------------------------------------------------
__global__ __launch_bounds__(256, 2)
void attn_kernel(const __bf16* __restrict__ hF, const float* __restrict__ a_src,
                 const float* __restrict__ a_dst,
                 const unsigned long long* __restrict__ abits,
                 float* __restrict__ out) {
  const int tid = threadIdx.x;
  const int b  = blockIdx.x & 7;           // XCD swizzle
  const int i0 = (blockIdx.x >> 3) * 32;

  const int w = tid >> 6, lane = tid & 63, col = lane & 15, q = lane >> 4;

  const size_t hl = (size_t)(b * HEADS_ + w);
  const float asr[2] = {a_src[(hl << 11) + i0 + col],
                        a_src[(hl << 11) + i0 + 16 + col]};
  const float* adb = a_dst + (hl << 11) + q * 8;
  const __bf16* hb = hF + hl * 131072 + lane * 8;              // 32*8*512
  const unsigned long long* bp0 = abits + (((size_t)b << 11) + i0 + col) * 32;
  const unsigned long long* bp1 = bp0 + (16 * 32);

  f32x4 acc[2][4];
#pragma unroll
  for (int mt = 0; mt < 2; ++mt)
#pragma unroll
    for (int nt = 0; nt < 4; ++nt) acc[mt][nt] = (f32x4)0.f;
  float lacc[2] = {0.f, 0.f};

  // current-tile regs (prologue: jt = 0)
  bf16x8 cb[2][4];
  float4 cd[2][2];
  unsigned long long cw0, cw1;
#pragma unroll
  for (int kt = 0; kt < 2; ++kt) {
#pragma unroll
    for (int nt = 0; nt < 4; ++nt)
      cb[kt][nt] = *(const bf16x8*)(hb + (kt * 4 + nt) * 512);
    cd[kt][0] = *(const float4*)(adb + kt * 32);
    cd[kt][1] = *(const float4*)(adb + kt * 32 + 4);
  }
  cw0 = bp0[0];
  cw1 = bp1[0];

#pragma unroll 2
  for (int jt = 0; jt < NJT; ++jt) {
    const int jn = (jt < NJT - 1) ? jt + 1 : jt;

    // ---- prefetch next tile (stays in flight through this tile's compute) ----
    bf16x8 nb[2][4];
    float4 nd[2][2];
#pragma unroll
    for (int kt = 0; kt < 2; ++kt) {
#pragma unroll
      for (int nt = 0; nt < 4; ++nt)
        nb[kt][nt] = *(const bf16x8*)(hb + jn * 4096 + (kt * 4 + nt) * 512);
      nd[kt][0] = *(const float4*)(adb + jn * 64 + kt * 32);
      nd[kt][1] = *(const float4*)(adb + jn * 64 + kt * 32 + 4);
    }
    const unsigned long long nw0 = bp0[jn];
    const unsigned long long nw1 = bp1[jn];

    // ---- phase 1: P in A-frag register order ----
    bf16x8 av[2][2];
#pragma unroll
    for (int mt = 0; mt < 2; ++mt) {
      const unsigned long long bw = mt ? cw1 : cw0;
#pragma unroll
      for (int kt = 0; kt < 2; ++kt) {
        const unsigned int tsh = ((unsigned int)(bw >> (kt * 32))) >> (q * 8);
        const float dd[8] = {cd[kt][0].x, cd[kt][0].y, cd[kt][0].z, cd[kt][0].w,
                             cd[kt][1].x, cd[kt][1].y, cd[kt][1].z, cd[kt][1].w};
        float ls = 0.f;
#pragma unroll
        for (int e = 0; e < 8; ++e) {
          float s = asr[mt] + dd[e];
          s = fmaxf(s, NEG_SLOPE_ * s);                 // leaky relu
          float p = ((tsh >> e) & 1u) ? __expf(s) : 0.f;
          ls += p;
          av[mt][kt][e] = (__bf16)p;
        }
        lacc[mt] += ls;
      }
    }

    // ---- phase 2: 16 MFMA ----
#pragma unroll
    for (int kt = 0; kt < 2; ++kt)
#pragma unroll
      for (int mt = 0; mt < 2; ++mt)
#pragma unroll
        for (int nt = 0; nt < 4; ++nt)
          acc[mt][nt] = __builtin_amdgcn_mfma_f32_16x16x32_bf16(
              av[mt][kt], cb[kt][nt], acc[mt][nt], 0, 0, 0);

    // rotate buffers
#pragma unroll
    for (int kt = 0; kt < 2; ++kt) {
#pragma unroll
      for (int nt = 0; nt < 4; ++nt) cb[kt][nt] = nb[kt][nt];
      cd[kt][0] = nd[kt][0];
      cd[kt][1] = nd[kt][1];
    }
    cw0 = nw0;
    cw1 = nw1;
  }

  // ---- l reduction: sum over the 4 q-lanes holding each row ----
#pragma unroll
  for (int mt = 0; mt < 2; ++mt) {
    lacc[mt] += __shfl_xor(lacc[mt], 16, 64);
    lacc[mt] += __shfl_xor(lacc[mt], 32, 64);
  }

  // ---- epilogue: out = acc / l (D row m = q*4+reg; l from lane col=m) ----
#pragma unroll
  for (int mt = 0; mt < 2; ++mt)
#pragma unroll
    for (int reg = 0; reg < 4; ++reg) {
      const int m = q * 4 + reg;
      const float linv = 1.0f / __shfl(lacc[mt], m, 64);
      const size_t orow =
          ((size_t)(b * L_ + i0 + mt * 16 + m)) * COUT_ + w * 64;
#pragma unroll
      for (int nt = 0; nt < 4; ++nt)
        out[orow + nt * 16 + col] = acc[mt][nt][reg] * linv;
    }
}

// ---------------------------------------------------------------------------
extern "C" void kernel_launch(void* const* d_in, const int* in_sizes, int n_in,
                              void* d_out, int out_size, void* d_ws, size_t ws_size,
                              hipStream_t stream) {
  const float* x       = (const float*)d_in[0];
  const int*   adj     = (const int*)d_in[1];
  const float* W       = (const float*)d_in[2];
  const float* att_src = (const float*)d_in[3];
  const float* att_dst = (const float*)d_in[4];
  float* out = (float*)d_out;

  char* ws = (char*)d_ws;
  __bf16* hF = (__bf16*)ws;                                   // 8 MB frag-linear
  float* a_src = (float*)(ws + (8u << 20));                   // 256 KB
  float* a_dst = (float*)(ws + (8u << 20) + (256u << 10));    // 256 KB
  unsigned long long* abits =
      (unsigned long long*)(ws + (8u << 20) + (512u << 10));  // 4 MB

  pack_kernel<<<(B_ * L_ * (L_ / 256)) / 4, 256, 0, stream>>>(adj, abits);
  proj_kernel<<<(B_ * L_) / TI, 256, 0, stream>>>(x, W, att_src, att_dst, hF, a_src, a_dst);
  attn_kernel<<<B_ * (L_ / 32), 256, 0, stream>>>(hF, a_src, a_dst, abits, out);
}